// Round 1
// baseline (919.091 us; speedup 1.0000x reference)
//
#include <hip/hip_runtime.h>

#define NX 128
#define NY 128
#define NT 16
#define NC 8
#define NRAD 2048

// ---------------------------------------------------------------------------
// Kernel 1: src[t][c][x][y] = (csmap[c,0,x,y] + i csmap[c,1,x,y]) *
//                             (x[0,x,y,t]   + i x[1,x,y,t])
// interleaved complex: src[(((t*NC+c)*NX+x)*NY+y)*2 + {0,1}]
// Precomputing this lets the forward kernel read it with wave-uniform
// (scalar, SMEM-pipe) loads so the VALU only does FMAs.
// ---------------------------------------------------------------------------
__global__ __launch_bounds__(256) void prep_src(const float* __restrict__ xin,
                                                const float* __restrict__ csmap,
                                                float* __restrict__ src) {
    const int t = blockIdx.x, c = blockIdx.y;
    const float* s0 = csmap + (size_t)(c * 2 + 0) * NX * NY;
    const float* s1 = csmap + (size_t)(c * 2 + 1) * NX * NY;
    float* dst = src + (size_t)(t * NC + c) * NX * NY * 2;
    for (int p = threadIdx.x; p < NX * NY; p += 256) {
        float sr = s0[p], si = s1[p];
        float ir = xin[(size_t)p * NT + t];
        float ii = xin[(size_t)NX * NY * NT + (size_t)p * NT + t];
        dst[2 * p]     = sr * ir - si * ii;
        dst[2 * p + 1] = sr * ii + si * ir;
    }
}

// ---------------------------------------------------------------------------
// Kernel 2 (forward NDFT): one thread per k-point, one block per (t, c, kblk).
// kdat[c,k] = sum_y Ey[k,y] * (sum_x Ex[k,x] * src[c,x,y]),  Ex=exp(-i kx*xs)
// g = kdat * dcomp * scale^2 written to ws (layout [t][k][c][2], 16 floats/k
// contiguous so the adjoint can scalar-load them).
// Ex/Ey are generated by unit-phasor recurrence (init via __sincosf).
// ---------------------------------------------------------------------------
__global__ __launch_bounds__(256) void fwd_kernel(const float* __restrict__ ktraj,
                                                  const float* __restrict__ dcomp,
                                                  const float* __restrict__ src,
                                                  float* __restrict__ g) {
    const int t = blockIdx.x, c = blockIdx.y;
    const int k = blockIdx.z * 256 + threadIdx.x;
    const float kx = ktraj[(size_t)(0 * NRAD + k) * NT + t];
    const float ky = ktraj[(size_t)(1 * NRAD + k) * NT + t];

    // step phasors: exp(-i kx) = (cos kx, -sin kx)
    float stxc, stxs; __sincosf(kx, &stxs, &stxc);
    float styc, stys; __sincosf(ky, &stys, &styc);

    float accr = 0.f, acci = 0.f;
    const float* sp_base = src + (size_t)(t * NC + c) * NX * NY * 2;

    for (int yb = 0; yb < NY; yb += 32) {
        float ar[32], ai[32];
#pragma unroll
        for (int y = 0; y < 32; ++y) { ar[y] = 0.f; ai[y] = 0.f; }

        // Ex at x=0: phase = -kx*(0-64) = +64*kx
        float exr, exi;
        __sincosf(kx * 64.0f, &exi, &exr);   // (cos, sin) of +64*kx

        for (int x = 0; x < NX; ++x) {
            const float* sp = sp_base + (size_t)(x * NY + yb) * 2;  // wave-uniform
#pragma unroll
            for (int y = 0; y < 32; ++y) {
                float sr = sp[2 * y], si = sp[2 * y + 1];
                ar[y] = fmaf(exr, sr, ar[y]);
                ar[y] = fmaf(-exi, si, ar[y]);
                ai[y] = fmaf(exr, si, ai[y]);
                ai[y] = fmaf(exi, sr, ai[y]);
            }
            // Ex *= exp(-i kx)
            float nr = fmaf(exr, stxc,  exi * stxs);
            float ni = fmaf(exi, stxc, -exr * stxs);
            exr = nr; exi = ni;
        }

        // Ey at y=yb: phase = -ky*(yb-64) = +ky*(64-yb)
        float eyr, eyi;
        __sincosf(ky * (float)(64 - yb), &eyi, &eyr);
#pragma unroll
        for (int y = 0; y < 32; ++y) {
            accr += eyr * ar[y] - eyi * ai[y];
            acci += eyr * ai[y] + eyi * ar[y];
            float nr = fmaf(eyr, styc,  eyi * stys);
            float ni = fmaf(eyi, styc, -eyr * stys);
            eyr = nr; eyi = ni;
        }
    }

    const float w = dcomp[(size_t)k * NT + t] * (1.0f / (float)(NX * NY)); // scale^2
    float* gp = g + (size_t)((t * NRAD + k) * NC + c) * 2;
    gp[0] = accr * w;
    gp[1] = acci * w;
}

// ---------------------------------------------------------------------------
// Kernel 3 (adjoint NDFT + coil combine): block = (frame t, 16x16 pixel tile).
// xim[c,x,y] = sum_k conj(Ex[k,x]) conj(Ey[k,y]) g[c,k]
// out[x,y]   = sum_c conj(smap[c,x,y]) * xim[c,x,y]
// Ex/Ey staged per 64-k chunk in LDS (sincos amortized over the tile);
// g[c,k] is wave-uniform per k -> scalar loads.
// ---------------------------------------------------------------------------
#define KC 64
__global__ __launch_bounds__(256) void adj_kernel(const float* __restrict__ ktraj,
                                                  const float* __restrict__ csmap,
                                                  const float* __restrict__ g,
                                                  float* __restrict__ out) {
    const int t = blockIdx.x;
    const int tileId = blockIdx.y;            // 64 tiles of 16x16
    const int xb = (tileId >> 3) * 16, yb = (tileId & 7) * 16;
    const int tx = threadIdx.x & 15, ty = threadIdx.x >> 4;
    const int x = xb + tx, y = yb + ty;

    __shared__ float exs[KC][16][2];
    __shared__ float eys[KC][16][2];

    float ximr[NC], ximi[NC];
#pragma unroll
    for (int c = 0; c < NC; ++c) { ximr[c] = 0.f; ximi[c] = 0.f; }

    for (int kb = 0; kb < NRAD; kb += KC) {
        __syncthreads();
        for (int i = threadIdx.x; i < KC * 16; i += 256) {
            int kk = i >> 4, j = i & 15;
            int kg = kb + kk;
            float kxv = ktraj[(size_t)(0 * NRAD + kg) * NT + t];
            float kyv = ktraj[(size_t)(1 * NRAD + kg) * NT + t];
            float sv, cv;
            __sincosf(kxv * (float)(xb + j - NX / 2), &sv, &cv);  // conj(Ex)=e^{+i kx xs}
            exs[kk][j][0] = cv; exs[kk][j][1] = sv;
            __sincosf(kyv * (float)(yb + j - NY / 2), &sv, &cv);
            eys[kk][j][0] = cv; eys[kk][j][1] = sv;
        }
        __syncthreads();

        const float* gp = g + (size_t)(t * NRAD + kb) * NC * 2;  // wave-uniform
        for (int kk = 0; kk < KC; ++kk) {
            float exr = exs[kk][tx][0], exi = exs[kk][tx][1];
            float eyr = eys[kk][ty][0], eyi = eys[kk][ty][1];
            float er = exr * eyr - exi * eyi;
            float ei = exr * eyi + exi * eyr;
            const float* gk = gp + kk * NC * 2;
#pragma unroll
            for (int c = 0; c < NC; ++c) {
                float gr = gk[2 * c], gi = gk[2 * c + 1];
                ximr[c] = fmaf(er, gr, ximr[c]);
                ximr[c] = fmaf(-ei, gi, ximr[c]);
                ximi[c] = fmaf(er, gi, ximi[c]);
                ximi[c] = fmaf(ei, gr, ximi[c]);
            }
        }
    }

    // coil combine with conj(smap)
    float outr = 0.f, outi = 0.f;
#pragma unroll
    for (int c = 0; c < NC; ++c) {
        float sr = csmap[(size_t)((c * 2 + 0) * NX + x) * NY + y];
        float si = csmap[(size_t)((c * 2 + 1) * NX + x) * NY + y];
        outr += sr * ximr[c] + si * ximi[c];
        outi += sr * ximi[c] - si * ximr[c];
    }
    out[(size_t)((0 * NX + x) * NY + y) * NT + t] = outr;
    out[(size_t)((1 * NX + x) * NY + y) * NT + t] = outi;
}

// ---------------------------------------------------------------------------
extern "C" void kernel_launch(void* const* d_in, const int* in_sizes, int n_in,
                              void* d_out, int out_size, void* d_ws, size_t ws_size,
                              hipStream_t stream) {
    const float* xin   = (const float*)d_in[0];  // (2,128,128,16)
    const float* ktraj = (const float*)d_in[1];  // (2,2048,16)
    const float* csmap = (const float*)d_in[2];  // (8,2,128,128)
    const float* dcomp = (const float*)d_in[3];  // (2048,16)
    float* out = (float*)d_out;                  // (2,128,128,16)

    // workspace layout: src (16 MB) | g (2 MB)
    float* src = (float*)d_ws;
    float* g   = (float*)((char*)d_ws + (size_t)NT * NC * NX * NY * 2 * sizeof(float));

    prep_src<<<dim3(NT, NC), 256, 0, stream>>>(xin, csmap, src);
    fwd_kernel<<<dim3(NT, NC, NRAD / 256), 256, 0, stream>>>(ktraj, dcomp, src, g);
    adj_kernel<<<dim3(NT, (NX / 16) * (NY / 16)), 256, 0, stream>>>(ktraj, csmap, g, out);
}

// Round 2
// 276.651 us; speedup vs baseline: 3.3222x; 3.3222x over previous
//
#include <hip/hip_runtime.h>

// Frame-wise E^H D E exact NDFT via separable phasors, restructured as two
// complex GEMMs on the fp16 matrix cores (fp32 accumulate):
//   fwd : C1[y,k] = sum_x src[c,y,x] * Ex[k,x]      (per t,c)  + fused y-reduce w/ Ey -> g[t,k,c]
//   adj : C3[(y,c),x] = sum_k t2[(y,c),k]*conj(Ex)  (per t)    + fused coil-combine -> out
// Complex mul done with K-interleaved real/imag and two accumulators (Cr,Ci);
// the second A-arrangement is derived in-register (rot16 / sign-xor).

#define NT 16
#define NK 2048
#define NXY 128
#define NC 8

typedef _Float16 f16x8 __attribute__((ext_vector_type(8)));
typedef float f32x4 __attribute__((ext_vector_type(4)));

union F8 { f16x8 h; uint u[4]; };

#define MFMA16(a, b, c) __builtin_amdgcn_mfma_f32_16x16x32_f16((a), (b), (c), 0, 0, 0)

__device__ __forceinline__ uint pack2h(float a, float b) {
    union { _Float16 h[2]; uint u; } p;
    p.h[0] = (_Float16)a; p.h[1] = (_Float16)b;
    return p.u;
}
__device__ __forceinline__ float2 unpack2h(uint v) {
    union { uint u; _Float16 h[2]; } p;
    p.u = v;
    return make_float2((float)p.h[0], (float)p.h[1]);
}
__device__ __forceinline__ uint rot16(uint v) { return (v >> 16) | (v << 16); }

// ---------------------------------------------------------------------------
// Tables: ExC[t][k][x] (k-major), ExT[t][x][k] (x-major), EyC[t][k][y].
// All complex fp16 packed in one dword. Unit-phasor recurrence per (t,k).
// Ex[k,x] = exp(-i*kx*(x-64)); start at x=0 -> exp(+i*64*kx), step exp(-i*kx).
// ---------------------------------------------------------------------------
__global__ __launch_bounds__(256) void prep_tables(const float* __restrict__ ktraj,
                                                   uint* __restrict__ ExC,
                                                   uint* __restrict__ ExT,
                                                   uint* __restrict__ EyC) {
    const int t = blockIdx.x;
    const int k = blockIdx.y * 256 + threadIdx.x;
    const float kx = ktraj[(size_t)k * NT + t];
    const float ky = ktraj[(size_t)(NK + k) * NT + t];

    {
        float er, ei, stc, sts;
        __sincosf(64.0f * kx, &ei, &er);
        __sincosf(kx, &sts, &stc);
        uint* exc = ExC + ((size_t)t * NK + k) * NXY;
        uint* ext = ExT + (size_t)t * NXY * NK + k;
        for (int x = 0; x < NXY; ++x) {
            uint p = pack2h(er, ei);
            exc[x] = p;
            ext[(size_t)x * NK] = p;
            float nr = er * stc + ei * sts;
            float ni = ei * stc - er * sts;
            er = nr; ei = ni;
        }
    }
    {
        float er, ei, stc, sts;
        __sincosf(64.0f * ky, &ei, &er);
        __sincosf(ky, &sts, &stc);
        uint* eyc = EyC + ((size_t)t * NK + k) * NXY;
        for (int y = 0; y < NXY; ++y) {
            eyc[y] = pack2h(er, ei);
            float nr = er * stc + ei * sts;
            float ni = ei * stc - er * sts;
            er = nr; ei = ni;
        }
    }
}

// ---------------------------------------------------------------------------
// srcB[t][c][y][x] = (smap[c,x,y] * img[x,y,t]) as packed complex fp16
// ---------------------------------------------------------------------------
__global__ __launch_bounds__(256) void prep_src(const float* __restrict__ xin,
                                                const float* __restrict__ csmap,
                                                uint* __restrict__ srcB) {
    const int idx = blockIdx.x * 256 + threadIdx.x;   // < 16*8*128*128
    const int x = idx & 127, y = (idx >> 7) & 127, c = (idx >> 14) & 7, t = idx >> 17;
    const float ir = xin[(size_t)(x * NXY + y) * NT + t];
    const float ii = xin[(size_t)NXY * NXY * NT + (size_t)(x * NXY + y) * NT + t];
    const float sr = csmap[(size_t)c * 2 * NXY * NXY + x * NXY + y];
    const float si = csmap[(size_t)c * 2 * NXY * NXY + NXY * NXY + x * NXY + y];
    srcB[(size_t)((t * NC + c) * NXY + y) * NXY + x] =
        pack2h(sr * ir - si * ii, sr * ii + si * ir);
}

// ---------------------------------------------------------------------------
// fwd_gemm: block = (t, c, ktile of 128 kpoints), 256 thr (4 waves).
// GEMM C1[y(m)=128, kpoint(n)=128] over K'=256 (x interleaved r/i), chunks of 32.
// A = srcB rows (LDS ping-pong, padded 40 halves/row), B = ExC rows (global).
// Epilogue: kdat[k] = sum_y Ey[k,y]*C1[y,k]; g = kdat * dcomp / 16384.
// ---------------------------------------------------------------------------
__global__ __launch_bounds__(256) void fwd_gemm(const uint* __restrict__ ExC,
                                                const uint* __restrict__ EyC,
                                                const uint* __restrict__ srcB,
                                                const float* __restrict__ dcomp,
                                                float2* __restrict__ g) {
    const int t = blockIdx.x, c = blockIdx.y, kt = blockIdx.z;
    const int tid = threadIdx.x, lane = tid & 63, ws = tid >> 6;
    const int quad = lane >> 4, l15 = lane & 15;

    __shared__ __align__(16) _Float16 As[2][128][40];   // 32 K'-halves + 8 pad

    f32x4 accr[8][2], acci[8][2];
#pragma unroll
    for (int mf = 0; mf < 8; ++mf)
#pragma unroll
        for (int nf = 0; nf < 2; ++nf) {
            accr[mf][nf] = (f32x4)0.0f;
            acci[mf][nf] = (f32x4)0.0f;
        }

    const uint* srcRow = srcB + (size_t)((t * NC + c) * NXY) * NXY;   // [y][x] dwords
    const uint* exRow  = ExC + ((size_t)t * NK + kt * 128) * NXY;     // [kp_local][x] dwords

    // stage chunk 0
#pragma unroll
    for (int p = 0; p < 2; ++p) {
        int lin = p * 256 + tid, y = lin >> 2, xi = lin & 3;
        F8 v = *(const F8*)(srcRow + y * NXY + xi * 4);
        *(F8*)&As[0][y][xi * 8] = v;
    }
    __syncthreads();

    for (int ch = 0; ch < 8; ++ch) {
        const int buf = ch & 1;
        F8 Bf[2];
#pragma unroll
        for (int nf = 0; nf < 2; ++nf) {
            int kp_local = ws * 32 + nf * 16 + l15;
            Bf[nf] = *(const F8*)(exRow + kp_local * NXY + ch * 16 + quad * 4);
        }
#pragma unroll
        for (int mf = 0; mf < 8; ++mf) {
            F8 Ap = *(const F8*)&As[buf][mf * 16 + l15][quad * 8];
            F8 Ar, Ai;
#pragma unroll
            for (int d = 0; d < 4; ++d) {
                Ar.u[d] = Ap.u[d] ^ 0x80000000u;   // (sR, -sI)
                Ai.u[d] = rot16(Ap.u[d]);          // (sI,  sR)
            }
#pragma unroll
            for (int nf = 0; nf < 2; ++nf) {
                accr[mf][nf] = MFMA16(Ar.h, Bf[nf].h, accr[mf][nf]);
                acci[mf][nf] = MFMA16(Ai.h, Bf[nf].h, acci[mf][nf]);
            }
        }
        if (ch < 7) {
#pragma unroll
            for (int p = 0; p < 2; ++p) {
                int lin = p * 256 + tid, y = lin >> 2, xi = lin & 3;
                F8 v = *(const F8*)(srcRow + y * NXY + (ch + 1) * 16 + xi * 4);
                *(F8*)&As[buf ^ 1][y][xi * 8] = v;
            }
        }
        __syncthreads();
    }

    // epilogue: y-reduction with Ey, then g
    const uint* eyRow = EyC + ((size_t)t * NK + kt * 128) * NXY;
#pragma unroll
    for (int nf = 0; nf < 2; ++nf) {
        const int kp_local = ws * 32 + nf * 16 + l15;
        const int kpoint = kt * 128 + kp_local;
        float kdr = 0.f, kdi = 0.f;
#pragma unroll
        for (int mf = 0; mf < 8; ++mf) {
            F8 e4 = *(const F8*)(eyRow + kp_local * NXY + mf * 16 + quad * 4);
#pragma unroll
            for (int r = 0; r < 4; ++r) {
                float2 ey = unpack2h(e4.u[r]);
                float cr = accr[mf][nf][r], ci = acci[mf][nf][r];
                kdr += ey.x * cr - ey.y * ci;
                kdi += ey.x * ci + ey.y * cr;
            }
        }
        kdr += __shfl_xor(kdr, 16); kdr += __shfl_xor(kdr, 32);
        kdi += __shfl_xor(kdi, 16); kdi += __shfl_xor(kdi, 32);
        if (lane < 16) {
            float w = dcomp[(size_t)kpoint * NT + t] * (1.0f / 16384.0f);
            g[((size_t)t * NK + kpoint) * NC + c] = make_float2(kdr * w, kdi * w);
        }
    }
}

// ---------------------------------------------------------------------------
// adj_gemm: block = (t, ytile of 8 y), 512 thr (8 waves).
// GEMM C3[m=(yloc*8+c)=64, x(n)=128] over K'=4096 (kpoints interleaved r/i),
// chunks of 64 halves (32 kpoints). A = t2 = conj(Ey)*g built in LDS ping-pong;
// B = ExT rows (global). Epilogue: coil-combine with conj(smap) -> out.
// ---------------------------------------------------------------------------
__global__ __launch_bounds__(512) void adj_gemm(const uint* __restrict__ ExT,
                                                const uint* __restrict__ EyC,
                                                const float2* __restrict__ g,
                                                const float* __restrict__ csmap,
                                                float* __restrict__ out) {
    const int t = blockIdx.x, yt = blockIdx.y, ybase = yt * 8;
    const int tid = threadIdx.x, lane = tid & 63, ws = tid >> 6;
    const int quad = lane >> 4, l15 = lane & 15;
    const int x = ws * 16 + l15;

    __shared__ __align__(16) _Float16 Ts[2][64][72];    // 64 K'-halves + 8 pad

    f32x4 accr[4], acci[4];
#pragma unroll
    for (int mf = 0; mf < 4; ++mf) { accr[mf] = (f32x4)0.0f; acci[mf] = (f32x4)0.0f; }

    const float2* gBase = g + (size_t)t * NK * NC;
    const uint* eyBase = EyC + (size_t)t * NK * NXY;
    const uint* exBase = ExT + (size_t)t * NXY * NK;

    const int bm = tid & 63;                 // build: row m
    const int bk4 = (tid >> 6) * 4;          // build: kpoint offset (0..28)
    const int by = ybase + (bm >> 3), bc = bm & 7;

    // build chunk 0
    {
        F8 w;
#pragma unroll
        for (int j = 0; j < 4; ++j) {
            int kp = bk4 + j;
            float2 gv = gBase[kp * NC + bc];
            float2 ey = unpack2h(eyBase[(size_t)kp * NXY + by]);
            w.u[j] = pack2h(ey.x * gv.x + ey.y * gv.y, ey.x * gv.y - ey.y * gv.x);
        }
        *(F8*)&Ts[0][bm][bk4 * 2] = w;
    }
    __syncthreads();

    for (int ch = 0; ch < 64; ++ch) {
        const int buf = ch & 1;
#pragma unroll
        for (int ks = 0; ks < 2; ++ks) {
            const int kp = ch * 32 + ks * 16 + quad * 4;
            F8 Bf = *(const F8*)(exBase + (size_t)x * NK + kp);
#pragma unroll
            for (int mf = 0; mf < 4; ++mf) {
                F8 Ap = *(const F8*)&Ts[buf][mf * 16 + l15][ks * 32 + quad * 8];
                F8 Ai;
#pragma unroll
                for (int d = 0; d < 4; ++d) Ai.u[d] = rot16(Ap.u[d]) ^ 0x80000000u; // (t2I, -t2R)
                accr[mf] = MFMA16(Ap.h, Bf.h, accr[mf]);
                acci[mf] = MFMA16(Ai.h, Bf.h, acci[mf]);
            }
        }
        if (ch < 63) {
            F8 w;
#pragma unroll
            for (int j = 0; j < 4; ++j) {
                int kp = (ch + 1) * 32 + bk4 + j;
                float2 gv = gBase[kp * NC + bc];
                float2 ey = unpack2h(eyBase[(size_t)kp * NXY + by]);
                w.u[j] = pack2h(ey.x * gv.x + ey.y * gv.y, ey.x * gv.y - ey.y * gv.x);
            }
            *(F8*)&Ts[buf ^ 1][bm][bk4 * 2] = w;
        }
        __syncthreads();
    }

    // epilogue: coil-combine with conj(smap), write out[2][x][y][t]
#pragma unroll
    for (int mf = 0; mf < 4; ++mf) {
        const int y = ybase + 2 * mf + (quad >> 1);
        float or_ = 0.f, oi_ = 0.f;
#pragma unroll
        for (int r = 0; r < 4; ++r) {
            int c = 4 * (quad & 1) + r;
            float sr = csmap[(size_t)c * 2 * NXY * NXY + x * NXY + y];
            float si = csmap[(size_t)c * 2 * NXY * NXY + NXY * NXY + x * NXY + y];
            float xr = accr[mf][r], xi = acci[mf][r];
            or_ += sr * xr + si * xi;
            oi_ += sr * xi - si * xr;
        }
        or_ += __shfl_xor(or_, 16);
        oi_ += __shfl_xor(oi_, 16);
        if ((lane & 16) == 0) {
            out[(size_t)(x * NXY + y) * NT + t] = or_;
            out[(size_t)NXY * NXY * NT + (size_t)(x * NXY + y) * NT + t] = oi_;
        }
    }
}

// ---------------------------------------------------------------------------
extern "C" void kernel_launch(void* const* d_in, const int* in_sizes, int n_in,
                              void* d_out, int out_size, void* d_ws, size_t ws_size,
                              hipStream_t stream) {
    const float* xin   = (const float*)d_in[0];  // (2,128,128,16)
    const float* ktraj = (const float*)d_in[1];  // (2,2048,16)
    const float* csmap = (const float*)d_in[2];  // (8,2,128,128)
    const float* dcomp = (const float*)d_in[3];  // (2048,16)
    float* out = (float*)d_out;                  // (2,128,128,16)

    // ws layout (dwords of packed complex fp16, then fp32 g): ~58 MB total
    const size_t TBL = (size_t)NT * NK * NXY;        // dwords per phasor table
    uint* ExC  = (uint*)d_ws;                        // [t][k][x]
    uint* ExT  = ExC + TBL;                          // [t][x][k]
    uint* EyC  = ExT + TBL;                          // [t][k][y]
    uint* srcB = EyC + TBL;                          // [t][c][y][x]
    float2* g  = (float2*)(srcB + (size_t)NT * NC * NXY * NXY);  // [t][k][c]

    prep_tables<<<dim3(NT, NK / 256), 256, 0, stream>>>(ktraj, ExC, ExT, EyC);
    prep_src<<<dim3((NT * NC * NXY * NXY) / 256), 256, 0, stream>>>(xin, csmap, srcB);
    fwd_gemm<<<dim3(NT, NC, NK / 128), 256, 0, stream>>>(ExC, EyC, srcB, dcomp, g);
    adj_gemm<<<dim3(NT, NXY / 8), 512, 0, stream>>>(ExT, EyC, g, csmap, out);
}